// Round 9
// baseline (281.800 us; speedup 1.0000x reference)
//
#include <hip/hip_runtime.h>

#define F 128
#define NBA 512        // D-side binning blocks
#define NBS 128        // S-side binning blocks (longer runs for 1-byte keys)
#define COARSE 256     // coarse buckets = node >> 8  (assumes N = 65536)
#define CAP_BIN 4864   // slot capacity per bucket, pre-sort (mean 4096, 12 sigma)
#define CAP_CSR 5632   // slot capacity per bucket, post-sort w/ per-row 4-align pads

typedef unsigned int uint;
typedef unsigned short ushort;
typedef unsigned char uchar;
typedef __attribute__((ext_vector_type(8))) short short8;
typedef __attribute__((ext_vector_type(8))) unsigned short ushort8;
typedef __attribute__((ext_vector_type(4))) float floatx4;

__device__ __forceinline__ ushort f2bf(float f) {
  uint u = __float_as_uint(f);
  u += 0x7fffu + ((u >> 16) & 1u);   // round-to-nearest-even
  return (ushort)(u >> 16);
}

// ---------------- W prep: fp32 [k][n] -> bf16 [n][k] (once, tiny) ----------------
__global__ __launch_bounds__(256) void w_prep(const float* __restrict__ W1,
                                              const float* __restrict__ W2,
                                              ushort* __restrict__ W1t,
                                              ushort* __restrict__ W2t) {
  int b = blockIdx.x;                         // 0..127
  const float* W = (b < 64) ? W1 : W2;
  ushort* Wt = (b < 64) ? W1t : W2t;
  int idx = (b & 63) * 256 + threadIdx.x;     // 0..16383
  int k = idx >> 7, n = idx & 127;
  Wt[n * F + k] = f2bf(W[idx]);
}

// ---------------- single-pass slotted binning ----------------
// Blocks [0,NBA): dst -> uint2{payload, fineKey} into slotted D regions (64 B runs).
// Blocks [NBA,NBA+NBS): src -> 1 B fine keys into S regions (32 B runs).
// Count phase uses per-wave sub-histograms; scatter uses a block-level cursor.
__global__ __launch_bounds__(256) void bin_edges(
    const int* __restrict__ src, const int* __restrict__ dst,
    const float* __restrict__ ew, int E,
    int* __restrict__ cursorD, int* __restrict__ cursorS,
    uint2* __restrict__ slotD, uchar* __restrict__ srcF) {
  __shared__ int cnt[4][COARSE];
  __shared__ int base[COARSE];
  bool isD = blockIdx.x < NBA;
  int blk = isD ? blockIdx.x : blockIdx.x - NBA;
  int nblk = isD ? NBA : NBS;
  const int* key = isD ? dst : src;
  int* cursor = isD ? cursorD : cursorS;
  int wave = threadIdx.x >> 6;
  for (int i = threadIdx.x; i < 4 * COARSE; i += 256) ((int*)cnt)[i] = 0;
  __syncthreads();
  int chunk = (E + nblk - 1) / nblk;
  int s0 = blk * chunk, s1 = min(E, s0 + chunk);
  for (int i = s0 + threadIdx.x; i < s1; i += 256)
    atomicAdd(&cnt[wave][key[i] >> 8], 1);
  __syncthreads();
  if (threadIdx.x < COARSE) {
    int b = threadIdx.x;
    int tot = cnt[0][b] + cnt[1][b] + cnt[2][b] + cnt[3][b];
    base[b] = tot ? atomicAdd(&cursor[b], tot) : 0;
    cnt[0][b] = 0;  // reuse row 0 as block-level scatter cursor
  }
  __syncthreads();
  if (isD) {
    for (int i = s0 + threadIdx.x; i < s1; i += 256) {
      int d = dst[i];
      int bin = d >> 8;
      int p = base[bin] + atomicAdd(&cnt[0][bin], 1);
      if (p < CAP_BIN) {
        uint2 v;
        v.x = (uint)(src[i] & 0xffff) | ((uint)f2bf(ew[i]) << 16);
        v.y = (uint)(d & 255);
        slotD[(size_t)bin * CAP_BIN + p] = v;
      }
    }
  } else {
    for (int i = s0 + threadIdx.x; i < s1; i += 256) {
      int s = src[i];
      int bin = s >> 8;
      int p = base[bin] + atomicAdd(&cnt[0][bin], 1);
      if (p < CAP_BIN) srcF[(size_t)bin * CAP_BIN + p] = (uchar)(s & 255);
    }
  }
}

// ---------------- per-bucket fine sort -> 4-aligned CSR rows ----------------
// Blocks [0,COARSE): D phase (hist/scan/scatter -> rowRange, inNorm, csr).
// Blocks [COARSE,2*COARSE): S phase (hist -> outNorm).
__global__ __launch_bounds__(1024) void bucket_csr(
    const uint2* __restrict__ slotD, const int* __restrict__ cursorD,
    int2* __restrict__ rowRange, float* __restrict__ inNorm, uint* __restrict__ csr,
    const uchar* __restrict__ srcF, const int* __restrict__ cursorS,
    float* __restrict__ outNorm) {
  __shared__ int hist[256], base[256], cur[256];
  int t = threadIdx.x;
  if (blockIdx.x >= COARSE) {   // ---- S phase: outNorm ----
    int b = blockIdx.x - COARSE;
    int lo = b * CAP_BIN;
    int cntS = min(cursorS[b], CAP_BIN);
    if (t < 256) hist[t] = 0;
    __syncthreads();
    for (int i = lo + t; i < lo + cntS; i += 1024)
      atomicAdd(&hist[srcF[i]], 1);
    __syncthreads();
    if (t < 256) outNorm[b * 256 + t] = rsqrtf((float)max(hist[t], 1));
    return;
  }
  // ---- D phase ----
  int b = blockIdx.x;
  int lo = b * CAP_BIN;
  int cntD = min(cursorD[b], CAP_BIN);
  int hi = lo + cntD;
  if (t < 256) hist[t] = 0;
  __syncthreads();
  for (int i = lo + t; i < hi; i += 1024)
    atomicAdd(&hist[slotD[i].y], 1);
  __syncthreads();
  // inclusive scan of round4(hist) -> aligned row starts
  if (t < 256) base[t] = (hist[t] + 3) & ~3;
  __syncthreads();
  for (int off = 1; off < 256; off <<= 1) {
    int x = 0;
    if (t < 256 && t >= off) x = base[t - off];
    __syncthreads();
    if (t < 256) base[t] += x;
    __syncthreads();
  }
  if (t < 256) {
    int v = hist[t];
    int sz4 = (v + 3) & ~3;
    int st = b * CAP_CSR + base[t] - sz4;
    base[t] = st;
    cur[t] = 0;
    int node = b * 256 + t;
    rowRange[node] = make_int2(st, v);
    inNorm[node] = rsqrtf((float)max(v, 1));
  }
  __syncthreads();
  for (int i = lo + t; i < hi; i += 1024) {
    uint2 v = slotD[i];
    int fine = v.y;
    int p = base[fine] + atomicAdd(&cur[fine], 1);
    csr[p] = v.x;
  }
}

// ---------------- MFMA GEMM ----------------
// BF16IN=0: Y = bf16((X_f32 * scale[:,None]) @ W);  BF16IN=1: Y = bf16(X_bf16 @ W)

template <bool BF16IN>
__global__ __launch_bounds__(256) void gemm_mfma(
    const void* __restrict__ Xv, const float* __restrict__ scale,
    const ushort* __restrict__ Wt, ushort* __restrict__ Y) {
  __shared__ ushort sA[128 * 136];
  __shared__ ushort sB[128 * 136];
  int t = threadIdx.x;
  int row0 = blockIdx.x * 128;

  {  // stage A
    int r = t >> 1, hf = t & 1;
    ushort* ap = sA + r * 136 + hf * 64;
    if (BF16IN) {
      const ushort* xp = (const ushort*)Xv + (size_t)(row0 + r) * F + hf * 64;
#pragma unroll
      for (int j = 0; j < 8; ++j)
        *(ushort8*)(ap + j * 8) = *(const ushort8*)(xp + j * 8);
    } else {
      const float* xp = (const float*)Xv + (size_t)(row0 + r) * F + hf * 64;
      float s = scale[row0 + r];
#pragma unroll
      for (int j = 0; j < 8; ++j) {
        float4 v0 = *(const float4*)(xp + j * 8);
        float4 v1 = *(const float4*)(xp + j * 8 + 4);
        ushort8 o;
        o[0] = f2bf(v0.x * s); o[1] = f2bf(v0.y * s); o[2] = f2bf(v0.z * s); o[3] = f2bf(v0.w * s);
        o[4] = f2bf(v1.x * s); o[5] = f2bf(v1.y * s); o[6] = f2bf(v1.z * s); o[7] = f2bf(v1.w * s);
        *(ushort8*)(ap + j * 8) = o;
      }
    }
  }
  {  // stage B: Wt (bf16 [n][k]) -> LDS copy
    int n = t >> 1, hf = t & 1;
    const ushort* wp = Wt + n * F + hf * 64;
    ushort* bp = sB + n * 136 + hf * 64;
#pragma unroll
    for (int j = 0; j < 8; ++j)
      *(ushort8*)(bp + j * 8) = *(const ushort8*)(wp + j * 8);
  }
  __syncthreads();

  int lane = t & 63, wave = t >> 6;
  int quad = lane >> 4, l16 = lane & 15;
  int mrow0 = wave * 32;

  floatx4 acc[2][8];
#pragma unroll
  for (int a = 0; a < 2; ++a)
#pragma unroll
    for (int c = 0; c < 8; ++c) acc[a][c] = (floatx4){0.f, 0.f, 0.f, 0.f};

#pragma unroll
  for (int kc = 0; kc < 128; kc += 32) {
    short8 afrag[2], bfrag[8];
#pragma unroll
    for (int a = 0; a < 2; ++a)
      afrag[a] = *(const short8*)(sA + (mrow0 + a * 16 + l16) * 136 + kc + quad * 8);
#pragma unroll
    for (int c = 0; c < 8; ++c)
      bfrag[c] = *(const short8*)(sB + (c * 16 + l16) * 136 + kc + quad * 8);
#pragma unroll
    for (int a = 0; a < 2; ++a)
#pragma unroll
      for (int c = 0; c < 8; ++c)
        acc[a][c] = __builtin_amdgcn_mfma_f32_16x16x32_bf16(afrag[a], bfrag[c], acc[a][c], 0, 0, 0);
  }

  // epilogue: C/D layout col=lane&15, row=quad*4+reg
#pragma unroll
  for (int a = 0; a < 2; ++a)
#pragma unroll
    for (int c = 0; c < 8; ++c)
#pragma unroll
      for (int r = 0; r < 4; ++r) {
        int row = row0 + mrow0 + a * 16 + quad * 4 + r;
        int col = c * 16 + l16;
        Y[(size_t)row * F + col] = f2bf(acc[a][c][r]);
      }
}

// ---------------- SpMM (gather over 4-aligned slotted dst-CSR, bf16 table) ----------------
// One 64-lane wave per dst node; lane holds dims {2*lane,2*lane+1} packed in a uint.
// CSR entry: src:16 | bf16(ew):16, rows 4-aligned -> uint4 edge loads.

template <bool EW, bool NB, bool RELU, bool PS, bool OUT_BF16>
__global__ __launch_bounds__(256) void spmm(
    const ushort* __restrict__ hb, const int2* __restrict__ rowRange,
    const uint* __restrict__ csr, const float* __restrict__ inNorm,
    const float* __restrict__ bias, const float* __restrict__ postScale,
    void* __restrict__ outv) {
  int node = blockIdx.x * 4 + (threadIdx.x >> 6);
  int lane = threadIdx.x & 63;
  int2 rr = rowRange[node];
  int base = rr.x, len = rr.y;

  float ax0 = 0.f, ay0 = 0.f, ax1 = 0.f, ay1 = 0.f;
  float ax2 = 0.f, ay2 = 0.f, ax3 = 0.f, ay3 = 0.f;
  int i = 0;
  for (; i + 8 <= len; i += 8) {
    uint4 c0 = *(const uint4*)(csr + base + i);
    uint4 c1 = *(const uint4*)(csr + base + i + 4);
    uint e0 = c0.x, e1 = c0.y, e2 = c0.z, e3 = c0.w;
    uint e4 = c1.x, e5 = c1.y, e6 = c1.z, e7 = c1.w;
    uint w0 = *((const uint*)(hb + ((size_t)(e0 & 0xffffu) << 7)) + lane);
    uint w1 = *((const uint*)(hb + ((size_t)(e1 & 0xffffu) << 7)) + lane);
    uint w2 = *((const uint*)(hb + ((size_t)(e2 & 0xffffu) << 7)) + lane);
    uint w3 = *((const uint*)(hb + ((size_t)(e3 & 0xffffu) << 7)) + lane);
    uint w4 = *((const uint*)(hb + ((size_t)(e4 & 0xffffu) << 7)) + lane);
    uint w5 = *((const uint*)(hb + ((size_t)(e5 & 0xffffu) << 7)) + lane);
    uint w6 = *((const uint*)(hb + ((size_t)(e6 & 0xffffu) << 7)) + lane);
    uint w7 = *((const uint*)(hb + ((size_t)(e7 & 0xffffu) << 7)) + lane);
    if (EW) {
      float q0 = __uint_as_float(e0 & 0xffff0000u), q1 = __uint_as_float(e1 & 0xffff0000u);
      float q2 = __uint_as_float(e2 & 0xffff0000u), q3 = __uint_as_float(e3 & 0xffff0000u);
      float q4 = __uint_as_float(e4 & 0xffff0000u), q5 = __uint_as_float(e5 & 0xffff0000u);
      float q6 = __uint_as_float(e6 & 0xffff0000u), q7 = __uint_as_float(e7 & 0xffff0000u);
      ax0 = fmaf(__uint_as_float(w0 << 16), q0, ax0); ay0 = fmaf(__uint_as_float(w0 & 0xffff0000u), q0, ay0);
      ax1 = fmaf(__uint_as_float(w1 << 16), q1, ax1); ay1 = fmaf(__uint_as_float(w1 & 0xffff0000u), q1, ay1);
      ax2 = fmaf(__uint_as_float(w2 << 16), q2, ax2); ay2 = fmaf(__uint_as_float(w2 & 0xffff0000u), q2, ay2);
      ax3 = fmaf(__uint_as_float(w3 << 16), q3, ax3); ay3 = fmaf(__uint_as_float(w3 & 0xffff0000u), q3, ay3);
      ax0 = fmaf(__uint_as_float(w4 << 16), q4, ax0); ay0 = fmaf(__uint_as_float(w4 & 0xffff0000u), q4, ay0);
      ax1 = fmaf(__uint_as_float(w5 << 16), q5, ax1); ay1 = fmaf(__uint_as_float(w5 & 0xffff0000u), q5, ay1);
      ax2 = fmaf(__uint_as_float(w6 << 16), q6, ax2); ay2 = fmaf(__uint_as_float(w6 & 0xffff0000u), q6, ay2);
      ax3 = fmaf(__uint_as_float(w7 << 16), q7, ax3); ay3 = fmaf(__uint_as_float(w7 & 0xffff0000u), q7, ay3);
    } else {
      ax0 += __uint_as_float(w0 << 16) + __uint_as_float(w4 << 16);
      ay0 += __uint_as_float(w0 & 0xffff0000u) + __uint_as_float(w4 & 0xffff0000u);
      ax1 += __uint_as_float(w1 << 16) + __uint_as_float(w5 << 16);
      ay1 += __uint_as_float(w1 & 0xffff0000u) + __uint_as_float(w5 & 0xffff0000u);
      ax2 += __uint_as_float(w2 << 16) + __uint_as_float(w6 << 16);
      ay2 += __uint_as_float(w2 & 0xffff0000u) + __uint_as_float(w6 & 0xffff0000u);
      ax3 += __uint_as_float(w3 << 16) + __uint_as_float(w7 << 16);
      ay3 += __uint_as_float(w3 & 0xffff0000u) + __uint_as_float(w7 & 0xffff0000u);
    }
  }
  if (i + 4 <= len) {   // full 4-group
    uint4 c = *(const uint4*)(csr + base + i);
    uint e0 = c.x, e1 = c.y, e2 = c.z, e3 = c.w;
    uint w0 = *((const uint*)(hb + ((size_t)(e0 & 0xffffu) << 7)) + lane);
    uint w1 = *((const uint*)(hb + ((size_t)(e1 & 0xffffu) << 7)) + lane);
    uint w2 = *((const uint*)(hb + ((size_t)(e2 & 0xffffu) << 7)) + lane);
    uint w3 = *((const uint*)(hb + ((size_t)(e3 & 0xffffu) << 7)) + lane);
    float q0 = EW ? __uint_as_float(e0 & 0xffff0000u) : 1.f;
    float q1 = EW ? __uint_as_float(e1 & 0xffff0000u) : 1.f;
    float q2 = EW ? __uint_as_float(e2 & 0xffff0000u) : 1.f;
    float q3 = EW ? __uint_as_float(e3 & 0xffff0000u) : 1.f;
    ax0 = fmaf(__uint_as_float(w0 << 16), q0, ax0); ay0 = fmaf(__uint_as_float(w0 & 0xffff0000u), q0, ay0);
    ax1 = fmaf(__uint_as_float(w1 << 16), q1, ax1); ay1 = fmaf(__uint_as_float(w1 & 0xffff0000u), q1, ay1);
    ax2 = fmaf(__uint_as_float(w2 << 16), q2, ax2); ay2 = fmaf(__uint_as_float(w2 & 0xffff0000u), q2, ay2);
    ax3 = fmaf(__uint_as_float(w3 << 16), q3, ax3); ay3 = fmaf(__uint_as_float(w3 & 0xffff0000u), q3, ay3);
    i += 4;
  }
  int r = len - i;      // 0..3 remaining; row is padded to round4 -> uint4 read safe
  if (r > 0) {
    uint4 c = *(const uint4*)(csr + base + i);
    uint ee[4] = {c.x, c.y, c.z, c.w};
#pragma unroll
    for (int j = 0; j < 3; ++j) {
      if (j < r) {      // wave-uniform branch
        uint wj = *((const uint*)(hb + ((size_t)(ee[j] & 0xffffu) << 7)) + lane);
        float q = EW ? __uint_as_float(ee[j] & 0xffff0000u) : 1.f;
        if (j == 0) { ax0 = fmaf(__uint_as_float(wj << 16), q, ax0); ay0 = fmaf(__uint_as_float(wj & 0xffff0000u), q, ay0); }
        if (j == 1) { ax1 = fmaf(__uint_as_float(wj << 16), q, ax1); ay1 = fmaf(__uint_as_float(wj & 0xffff0000u), q, ay1); }
        if (j == 2) { ax2 = fmaf(__uint_as_float(wj << 16), q, ax2); ay2 = fmaf(__uint_as_float(wj & 0xffff0000u), q, ay2); }
      }
    }
  }
  float rx = (ax0 + ax1) + (ax2 + ax3);
  float ry = (ay0 + ay1) + (ay2 + ay3);
  if (NB) {
    float sc = inNorm[node];
    float2 b = *((const float2*)bias + lane);
    rx = fmaf(rx, sc, b.x);
    ry = fmaf(ry, sc, b.y);
    if (RELU) { rx = fmaxf(rx, 0.f); ry = fmaxf(ry, 0.f); }
    if (PS) { float o = postScale[node]; rx *= o; ry *= o; }
  }
  if (OUT_BF16) {
    uint p = ((uint)f2bf(ry) << 16) | (uint)f2bf(rx);
    *((uint*)outv + ((size_t)node << 6) + lane) = p;
  } else {
    float2 rv = {rx, ry};
    *((float2*)outv + ((size_t)node << 6) + lane) = rv;
  }
}

// ---------------- launch ----------------

extern "C" void kernel_launch(void* const* d_in, const int* in_sizes, int n_in,
                              void* d_out, int out_size, void* d_ws, size_t ws_size,
                              hipStream_t stream) {
  const float* feat = (const float*)d_in[0];
  const float* ew   = (const float*)d_in[1];
  const float* W1   = (const float*)d_in[2];
  const float* b1   = (const float*)d_in[3];
  const float* W2   = (const float*)d_in[4];
  const float* b2   = (const float*)d_in[5];
  const int*   src  = (const int*)d_in[6];
  const int*   dst  = (const int*)d_in[7];
  const int N = in_sizes[0] / F;   // 65536 (COARSE math assumes this)
  const int E = in_sizes[6];
  float* out = (float*)d_out;

  char* ws = (char*)d_ws;
  size_t off = 0;
  auto alloc = [&](size_t bytes) {
    void* p = ws + off;
    off += (bytes + 255) & ~(size_t)255;
    return p;
  };
  // persistent
  int2*   rowRange = (int2*)alloc((size_t)N * 8);
  float*  inNorm   = (float*)alloc((size_t)N * 4);
  float*  outNorm  = (float*)alloc((size_t)N * 4);
  ushort* W1t      = (ushort*)alloc((size_t)F * F * 2);
  ushort* W2t      = (ushort*)alloc((size_t)F * F * 2);
  int*    cursorD  = (int*)alloc(COARSE * 4);   // contiguous with cursorS (one memset)
  int*    cursorS  = (int*)alloc(COARSE * 4);
  uint*   csr      = (uint*)alloc((size_t)COARSE * CAP_CSR * 4);
  ushort* bufAb    = (ushort*)alloc((size_t)N * F * 2);  // gathered table (layers 1&2)
  ushort* bufBb    = (ushort*)alloc((size_t)N * F * 2);  // h1pre bf16; bin scratch aliases
  ushort* bufCb    = (ushort*)alloc((size_t)N * F * 2);  // h2 bf16 (final gather)
  if (off > ws_size) return;

  // transient binning scratch aliased into bufBb (dead before spmm1 writes it)
  uint2* slotD;
  uchar* srcF;
  {
    char* tp = (char*)bufBb;
    size_t toff = 0;
    auto talloc = [&](size_t bytes) {
      void* p = tp + toff;
      toff += (bytes + 255) & ~(size_t)255;
      return p;
    };
    slotD = (uint2*)talloc((size_t)COARSE * CAP_BIN * 8);   // 9.96 MB
    srcF  = (uchar*)talloc((size_t)COARSE * CAP_BIN);       // 1.25 MB  (total 11.2 < 16 MB)
  }

  hipMemsetAsync(cursorD, 0, 2 * COARSE * 4, stream);  // cursors hold in-bucket offsets
  w_prep<<<128, 256, 0, stream>>>(W1, W2, W1t, W2t);
  bin_edges<<<NBA + NBS, 256, 0, stream>>>(src, dst, ew, E, cursorD, cursorS, slotD, srcF);
  bucket_csr<<<2 * COARSE, 1024, 0, stream>>>(slotD, cursorD, rowRange, inNorm, csr,
                                              srcF, cursorS, outNorm);

  // layer 1: h1pre = bf16( relu(SpMM(bf16((feat*outNorm)@W1)) * inNorm + b1) * outNorm )
  gemm_mfma<false><<<N / 128, 256, 0, stream>>>(feat, outNorm, W1t, bufAb);
  spmm<false, true, true, true, true><<<N / 4, 256, 0, stream>>>(
      bufAb, rowRange, csr, inNorm, b1, outNorm, bufBb);
  // layer 2: h2 = bf16( SpMM(bf16(h1pre@W2)) * inNorm + b2 )
  gemm_mfma<true><<<N / 128, 256, 0, stream>>>(bufBb, nullptr, W2t, bufAb);
  spmm<false, true, false, false, true><<<N / 4, 256, 0, stream>>>(
      bufAb, rowRange, csr, inNorm, b2, nullptr, bufCb);
  // final: out = segment_sum(h2[src] * eweight, dst)   [fp32 out]
  spmm<true, false, false, false, false><<<N / 4, 256, 0, stream>>>(
      bufCb, rowRange, csr, nullptr, nullptr, nullptr, out);
}